// Round 1
// baseline (263.218 us; speedup 1.0000x reference)
//
#include <hip/hip_runtime.h>

#define NSCALES 20
#define BATCH 16
#define PATCH 100
#define IMGS_PER_SCALE (BATCH * PATCH)   // 1600
#define TOTAL_IMGS (NSCALES * IMGS_PER_SCALE)  // 32000
#define SMAX 41
#define S2MAX (SMAX * SMAX)              // 1681
#define THREADS 256

struct Ptrs {
    const float* p[NSCALES];
};

// ---------------------------------------------------------------------------
// Kernel B: per-image features. One block per (scale, b, p) image.
// Computes: fg count, #components, max component size  -> workspace ints.
// ---------------------------------------------------------------------------
__global__ __launch_bounds__(THREADS)
void image_kernel(Ptrs ptrs, int* __restrict__ wsCounts,
                  int* __restrict__ wsNcomp, int* __restrict__ wsMaxc)
{
    const int scale = blockIdx.x / IMGS_PER_SCALE;
    const int img   = blockIdx.x - scale * IMGS_PER_SCALE;   // bb*100 + pp
    const int s  = 3 + 2 * scale;
    const int s2 = s * s;
    const int BIGL = s2 + 1;
    const float* __restrict__ x = ptrs.p[scale];
    const int tid = threadIdx.x;

    __shared__ int   lab[S2MAX];
    __shared__ int   szh[S2MAX];
    __shared__ float cen[SMAX * 3];
    __shared__ int   rs[4], rn[4], rm[4];
    __shared__ int   chg;

    // --- centers for each row i1 of this image (TF reshape semantics) ---
    // r = x.reshape(b*s, p, s, c); row j = (img*s + i1) / 100;
    // center = r[j, 49, (s-1)/2, :]
    for (int i1 = tid; i1 < s; i1 += THREADS) {
        int M  = img * s + i1;
        int j  = M / PATCH;
        int Mc = j * PATCH + 49;                 // (p-1)//2 = 49
        int base = (Mc * s + (s - 1) / 2) * 3;
        cen[i1 * 3 + 0] = x[base + 0];
        cen[i1 * 3 + 1] = x[base + 1];
        cen[i1 * 3 + 2] = x[base + 2];
    }
    __syncthreads();

    // --- binarize + init labels + fg count ---
    int cnt = 0;
    const int ibase = img * s2 * 3;              // < 8.1M, fits int
    for (int i = tid; i < s2; i += THREADS) {
        int i1 = i / s;
        float a0 = x[ibase + i * 3 + 0];
        float a1 = x[ibase + i * 3 + 1];
        float a2 = x[ibase + i * 3 + 2];
        float d = fmaxf(fmaxf(fabsf(a0 - cen[i1 * 3 + 0]),
                              fabsf(a1 - cen[i1 * 3 + 1])),
                        fabsf(a2 - cen[i1 * 3 + 2]));
        bool fg = (d <= (float)s);
        lab[i] = fg ? (i + 1) : BIGL;
        cnt += fg ? 1 : 0;
    }
    __syncthreads();

    // --- connected components: min-label propagation + pointer jumping ---
    // Fixed point (min flat idx in component + 1) is identical to the
    // reference's Jacobi iteration; Gauss-Seidel + jump converges faster.
    for (;;) {
        if (tid == 0) chg = 0;
        __syncthreads();
        for (int i = tid; i < s2; i += THREADS) {
            int L0 = lab[i];
            if (L0 <= s2) {
                int i1 = i / s;
                int i2 = i - i1 * s;
                int m = L0;
                if (i1 > 0)      m = min(m, lab[i - s]);
                if (i1 < s - 1)  m = min(m, lab[i + s]);
                if (i2 > 0)      m = min(m, lab[i - 1]);
                if (i2 < s - 1)  m = min(m, lab[i + 1]);
                m = min(m, lab[m - 1]);          // pointer jump
                if (m < L0) { lab[i] = m; chg = 1; }
            }
        }
        __syncthreads();
        int done = (chg == 0);
        __syncthreads();
        if (done) break;
    }

    // --- component sizes / root count ---
    for (int i = tid; i < s2; i += THREADS) szh[i] = 0;
    __syncthreads();
    int ncomp = 0;
    for (int i = tid; i < s2; i += THREADS) {
        int L0 = lab[i];
        if (L0 <= s2) {
            atomicAdd(&szh[L0 - 1], 1);
            if (L0 == i + 1) ncomp++;
        }
    }
    __syncthreads();
    int mc = 0;
    for (int i = tid; i < s2; i += THREADS) mc = max(mc, szh[i]);

    // --- block reductions (sum cnt, sum ncomp, max mc) ---
    for (int m = 32; m >= 1; m >>= 1) {
        cnt   += __shfl_xor(cnt, m);
        ncomp += __shfl_xor(ncomp, m);
        mc     = max(mc, __shfl_xor(mc, m));
    }
    int wid = tid >> 6, lane = tid & 63;
    if (lane == 0) { rs[wid] = cnt; rn[wid] = ncomp; rm[wid] = mc; }
    __syncthreads();
    if (tid == 0) {
        int C = 0, N = 0, M2 = 0;
        for (int w = 0; w < 4; w++) { C += rs[w]; N += rn[w]; M2 = max(M2, rm[w]); }
        int g = blockIdx.x;                      // scale*1600 + img
        wsCounts[g] = C;
        wsNcomp[g]  = N;
        wsMaxc[g]   = M2;
    }
}

// ---------------------------------------------------------------------------
// Kernel C: per-scale finalization. One block per scale.
// ---------------------------------------------------------------------------
__global__ __launch_bounds__(THREADS)
void final_kernel(const int* __restrict__ wsCounts,
                  const int* __restrict__ wsNcomp,
                  const int* __restrict__ wsMaxc,
                  float* __restrict__ out)
{
    const int scale = blockIdx.x;
    const int s  = 3 + 2 * scale;
    const int s2 = s * s;
    const int tid = threadIdx.x;
    const int NB = IMGS_PER_SCALE;               // 1600
    const int CH = 7;                            // ceil(1600/256)

    __shared__ int nc[IMGS_PER_SCALE];
    __shared__ int tsum[THREADS];

    for (int i = tid; i < NB; i += THREADS) nc[i] = wsNcomp[scale * NB + i];
    __syncthreads();

    // inclusive scan of ncomp over the whole (b*p) batch (global labels)
    int lsum = 0;
    for (int k = 0; k < CH; k++) {
        int idx = tid * CH + k;
        if (idx < NB) lsum += nc[idx];
    }
    tsum[tid] = lsum;
    __syncthreads();
    for (int st = 1; st < THREADS; st <<= 1) {
        int v = (tid >= st) ? tsum[tid - st] : 0;
        __syncthreads();
        tsum[tid] += v;
        __syncthreads();
    }
    int run = (tid > 0) ? tsum[tid - 1] : 0;     // exclusive prefix
    for (int k = 0; k < CH; k++) {
        int idx = tid * CH + k;
        if (idx < NB) {
            int v = nc[idx];
            run += v;
            nc[idx] = (v > 0) ? run : 0;         // maxlab
        }
    }
    __syncthreads();

    // per-sample (b) reductions over p=100: 16 groups x 16 lanes
    int b    = tid >> 4;
    int lane = tid & 15;
    float fdsum = 0.f, sn = 0.f, sn2 = 0.f, pcsum = 0.f;
    int pqc = 0, bg = 0, mcx = 0;
    for (int q = lane; q < PATCH; q += 16) {
        int i = b * PATCH + q;
        int c = wsCounts[scale * NB + i];
        float n = (c > 0) ? (float)c : 1.0f;     // numbers[0] = 1
        fdsum += 1.0f / n;
        sn    += n;
        sn2   += n * n;
        pqc   += ((float)c / (float)s2 >= 0.59275f) ? 1 : 0;
        bg    += (s2 - c);
        mcx    = max(mcx, wsMaxc[scale * NB + i]);
        pcsum += (float)nc[i];
    }
    for (int m = 8; m >= 1; m >>= 1) {
        fdsum += __shfl_xor(fdsum, m);
        sn    += __shfl_xor(sn, m);
        sn2   += __shfl_xor(sn2, m);
        pcsum += __shfl_xor(pcsum, m);
        pqc   += __shfl_xor(pqc, m);
        bg    += __shfl_xor(bg, m);
        mcx    = max(mcx, __shfl_xor(mcx, m));
    }
    if (lane == 0) {
        float fd  = fdsum / 100.0f;
        float m1  = sn / 100.0f;
        float mu1 = m1 * m1;
        float mu2 = sn2 / 100.0f;
        float lac = (mu2 - mu1) / mu1;
        float pq  = (float)pqc / 100.0f;
        float pc  = pcsum / 100.0f;
        float pm  = (float)max(bg, mcx);
        // out layout: (16,100) row-major; col = feature*20 + scale
        out[b * 100 +  0 + scale] = pc;
        out[b * 100 + 20 + scale] = pq;
        out[b * 100 + 40 + scale] = pm;
        out[b * 100 + 60 + scale] = lac;
        out[b * 100 + 80 + scale] = fd;
    }
}

extern "C" void kernel_launch(void* const* d_in, const int* in_sizes, int n_in,
                              void* d_out, int out_size, void* d_ws, size_t ws_size,
                              hipStream_t stream)
{
    Ptrs ptrs;
    for (int i = 0; i < NSCALES; i++) ptrs.p[i] = (const float*)d_in[i];

    int* wsC = (int*)d_ws;
    int* wsN = wsC + TOTAL_IMGS;
    int* wsM = wsN + TOTAL_IMGS;

    image_kernel<<<TOTAL_IMGS, THREADS, 0, stream>>>(ptrs, wsC, wsN, wsM);
    final_kernel<<<NSCALES, THREADS, 0, stream>>>(wsC, wsN, wsM, (float*)d_out);
}

// Round 2
// 70.104 us; speedup vs baseline: 3.7547x; 3.7547x over previous
//
#include <hip/hip_runtime.h>

#define NSCALES 20
#define BATCH 16
#define PATCH 100
#define IMGS_PER_SCALE (BATCH * PATCH)          // 1600
#define TOTAL_IMGS (NSCALES * IMGS_PER_SCALE)   // 32000
#define SMAX 41
#define S2MAX (SMAX * SMAX)                     // 1681
#define THREADS 256
#define MAXPX 7                                 // ceil(1681/256)

struct Ptrs {
    const float* p[NSCALES];
};

// ---------------------------------------------------------------------------
// Kernel B: per-image features. One block per (scale, b, p) image.
// Fast path: if every pixel is foreground (the overwhelmingly common case for
// s >= 7 given N(0,1) inputs and threshold d <= s), the answer is known
// analytically: cnt = s^2, ncomp = 1, maxcomp = s^2. No CC, no histogram.
// ---------------------------------------------------------------------------
__global__ __launch_bounds__(THREADS)
void image_kernel(Ptrs ptrs, int* __restrict__ wsCounts,
                  int* __restrict__ wsNcomp, int* __restrict__ wsMaxc)
{
    const int scale = blockIdx.x / IMGS_PER_SCALE;
    const int img   = blockIdx.x - scale * IMGS_PER_SCALE;   // bb*100 + pp
    const int s  = 3 + 2 * scale;
    const int s2 = s * s;
    const int BIGL = s2 + 1;
    const float* __restrict__ x = ptrs.p[scale];
    const int tid = threadIdx.x;
    // magic multiply for i / s (s odd, i < 1681): exact since n*e/(d*2^32) << 1/d
    const unsigned magic = 0xFFFFFFFFu / (unsigned)s + 1;

    __shared__ int   lab[S2MAX];
    __shared__ int   szh[S2MAX];
    __shared__ float cen[SMAX * 3];
    __shared__ int   red[4], redN[4], redM[4];

    // --- centers for each row i1 of this image (TF reshape semantics) ---
    // r = x.reshape(b*s, p, s, c); row j = (img*s + i1) / 100;
    // center = r[j, 49, (s-1)/2, :]
    for (int i1 = tid; i1 < s; i1 += THREADS) {
        int M  = img * s + i1;
        int j  = M / PATCH;
        int base = ((j * PATCH + 49) * s + (s >> 1)) * 3;
        cen[i1 * 3 + 0] = x[base + 0];
        cen[i1 * 3 + 1] = x[base + 1];
        cen[i1 * 3 + 2] = x[base + 2];
    }
    __syncthreads();

    // --- binarize into registers: fg bitmask + neighbor-availability mask ---
    int fgm = 0;     // bit k: pixel (tid + k*256) is foreground
    int nbm = 0;     // 4 bits per k: up|down|left|right neighbor exists
    int cnt = 0;
    const int ibase = img * s2 * 3;              // < 8.1M, fits int
    const float fs = (float)s;
    #pragma unroll
    for (int k = 0; k < MAXPX; k++) {
        int i = tid + k * THREADS;
        if (i < s2) {
            int i1 = (int)__umulhi((unsigned)i, magic);
            int i2 = i - i1 * s;
            const float* px = x + ibase + i * 3;
            float d0 = fabsf(px[0] - cen[i1 * 3 + 0]);
            float d1 = fabsf(px[1] - cen[i1 * 3 + 1]);
            float d2 = fabsf(px[2] - cen[i1 * 3 + 2]);
            float d  = fmaxf(fmaxf(d0, d1), d2);
            if (d <= fs) { fgm |= 1 << k; cnt++; }
            int b = (i1 > 0 ? 1 : 0) | (i1 < s - 1 ? 2 : 0)
                  | (i2 > 0 ? 4 : 0) | (i2 < s - 1 ? 8 : 0);
            nbm |= b << (4 * k);
        }
    }

    // --- block-reduce cnt ---
    int wc = cnt;
    for (int m = 32; m >= 1; m >>= 1) wc += __shfl_xor(wc, m);
    const int wid = tid >> 6, lane = tid & 63;
    if (lane == 0) red[wid] = wc;
    __syncthreads();
    const int total = red[0] + red[1] + red[2] + red[3];

    if (total == s2) {                           // all-foreground fast path
        if (tid == 0) {
            wsCounts[blockIdx.x] = s2;
            wsNcomp[blockIdx.x]  = 1;
            wsMaxc[blockIdx.x]   = s2;
        }
        return;
    }
    if (total == 0) {                            // no foreground at all
        if (tid == 0) {
            wsCounts[blockIdx.x] = 0;
            wsNcomp[blockIdx.x]  = 0;
            wsMaxc[blockIdx.x]   = 0;
        }
        return;
    }

    // --- slow path: init labels in LDS ---
    #pragma unroll
    for (int k = 0; k < MAXPX; k++) {
        int i = tid + k * THREADS;
        if (i < s2) lab[i] = ((fgm >> k) & 1) ? (i + 1) : BIGL;
    }
    __syncthreads();

    // --- CC: min-label propagation + pointer jumping; exact same fixed point
    //     as the reference's Jacobi loop (min flat index per component + 1).
    for (;;) {
        bool changed = false;
        #pragma unroll
        for (int k = 0; k < MAXPX; k++) {
            if ((fgm >> k) & 1) {
                int i  = tid + k * THREADS;
                int L0 = lab[i];
                int b  = nbm >> (4 * k);
                int m  = L0;
                if (b & 1) m = min(m, lab[i - s]);
                if (b & 2) m = min(m, lab[i + s]);
                if (b & 4) m = min(m, lab[i - 1]);
                if (b & 8) m = min(m, lab[i + 1]);
                m = min(m, lab[m - 1]);          // pointer jump
                if (m < L0) { lab[i] = m; changed = true; }
            }
        }
        if (__syncthreads_count(changed ? 1 : 0) == 0) break;
    }

    // --- component sizes / root count (rare path; tiny images dominate) ---
    #pragma unroll
    for (int k = 0; k < MAXPX; k++) {
        int i = tid + k * THREADS;
        if (i < s2) szh[i] = 0;
    }
    __syncthreads();
    int ncomp = 0;
    #pragma unroll
    for (int k = 0; k < MAXPX; k++) {
        if ((fgm >> k) & 1) {
            int i = tid + k * THREADS;
            int L = lab[i];
            atomicAdd(&szh[L - 1], 1);
            if (L == i + 1) ncomp++;
        }
    }
    __syncthreads();
    int mc = 0;
    #pragma unroll
    for (int k = 0; k < MAXPX; k++) {
        int i = tid + k * THREADS;
        if (i < s2) mc = max(mc, szh[i]);
    }

    for (int m = 32; m >= 1; m >>= 1) {
        ncomp += __shfl_xor(ncomp, m);
        mc     = max(mc, __shfl_xor(mc, m));
    }
    if (lane == 0) { redN[wid] = ncomp; redM[wid] = mc; }
    __syncthreads();
    if (tid == 0) {
        int N = redN[0] + redN[1] + redN[2] + redN[3];
        int M2 = max(max(redM[0], redM[1]), max(redM[2], redM[3]));
        wsCounts[blockIdx.x] = total;
        wsNcomp[blockIdx.x]  = N;
        wsMaxc[blockIdx.x]   = M2;
    }
}

// ---------------------------------------------------------------------------
// Kernel C: per-scale finalization. One block per scale. (negligible cost)
// ---------------------------------------------------------------------------
__global__ __launch_bounds__(THREADS)
void final_kernel(const int* __restrict__ wsCounts,
                  const int* __restrict__ wsNcomp,
                  const int* __restrict__ wsMaxc,
                  float* __restrict__ out)
{
    const int scale = blockIdx.x;
    const int s  = 3 + 2 * scale;
    const int s2 = s * s;
    const int tid = threadIdx.x;
    const int NB = IMGS_PER_SCALE;               // 1600
    const int CH = 7;                            // ceil(1600/256)

    __shared__ int nc[IMGS_PER_SCALE];
    __shared__ int tsum[THREADS];

    for (int i = tid; i < NB; i += THREADS) nc[i] = wsNcomp[scale * NB + i];
    __syncthreads();

    // inclusive scan of ncomp over the whole (b*p) batch (global labels)
    int lsum = 0;
    for (int k = 0; k < CH; k++) {
        int idx = tid * CH + k;
        if (idx < NB) lsum += nc[idx];
    }
    tsum[tid] = lsum;
    __syncthreads();
    for (int st = 1; st < THREADS; st <<= 1) {
        int v = (tid >= st) ? tsum[tid - st] : 0;
        __syncthreads();
        tsum[tid] += v;
        __syncthreads();
    }
    int run = (tid > 0) ? tsum[tid - 1] : 0;     // exclusive prefix
    for (int k = 0; k < CH; k++) {
        int idx = tid * CH + k;
        if (idx < NB) {
            int v = nc[idx];
            run += v;
            nc[idx] = (v > 0) ? run : 0;         // maxlab
        }
    }
    __syncthreads();

    // per-sample (b) reductions over p=100: 16 groups x 16 lanes
    int b    = tid >> 4;
    int lane = tid & 15;
    float fdsum = 0.f, sn = 0.f, sn2 = 0.f, pcsum = 0.f;
    int pqc = 0, bg = 0, mcx = 0;
    for (int q = lane; q < PATCH; q += 16) {
        int i = b * PATCH + q;
        int c = wsCounts[scale * NB + i];
        float n = (c > 0) ? (float)c : 1.0f;     // numbers[0] = 1
        fdsum += 1.0f / n;
        sn    += n;
        sn2   += n * n;
        pqc   += ((float)c / (float)s2 >= 0.59275f) ? 1 : 0;
        bg    += (s2 - c);
        mcx    = max(mcx, wsMaxc[scale * NB + i]);
        pcsum += (float)nc[i];
    }
    for (int m = 8; m >= 1; m >>= 1) {
        fdsum += __shfl_xor(fdsum, m);
        sn    += __shfl_xor(sn, m);
        sn2   += __shfl_xor(sn2, m);
        pcsum += __shfl_xor(pcsum, m);
        pqc   += __shfl_xor(pqc, m);
        bg    += __shfl_xor(bg, m);
        mcx    = max(mcx, __shfl_xor(mcx, m));
    }
    if (lane == 0) {
        float fd  = fdsum / 100.0f;
        float m1  = sn / 100.0f;
        float mu1 = m1 * m1;
        float mu2 = sn2 / 100.0f;
        float lac = (mu2 - mu1) / mu1;
        float pq  = (float)pqc / 100.0f;
        float pc  = pcsum / 100.0f;
        float pm  = (float)max(bg, mcx);
        // out layout: (16,100) row-major; col = feature*20 + scale
        out[b * 100 +  0 + scale] = pc;
        out[b * 100 + 20 + scale] = pq;
        out[b * 100 + 40 + scale] = pm;
        out[b * 100 + 60 + scale] = lac;
        out[b * 100 + 80 + scale] = fd;
    }
}

extern "C" void kernel_launch(void* const* d_in, const int* in_sizes, int n_in,
                              void* d_out, int out_size, void* d_ws, size_t ws_size,
                              hipStream_t stream)
{
    Ptrs ptrs;
    for (int i = 0; i < NSCALES; i++) ptrs.p[i] = (const float*)d_in[i];

    int* wsC = (int*)d_ws;
    int* wsN = wsC + TOTAL_IMGS;
    int* wsM = wsN + TOTAL_IMGS;

    image_kernel<<<TOTAL_IMGS, THREADS, 0, stream>>>(ptrs, wsC, wsN, wsM);
    final_kernel<<<NSCALES, THREADS, 0, stream>>>(wsC, wsN, wsM, (float*)d_out);
}